// Round 2
// baseline (3121.704 us; speedup 1.0000x reference)
//
#include <hip/hip_runtime.h>

// LiquidNeuralNetwork: B=512, S=1024, IN=16, HID=64, OUT=1, N_SUB=4 (RK4).
// One chain per wave (512 blocks x 64 thr), latency-bound serial chain.
// Round 2: replace the per-eval LDS tanh broadcast (ds_write_b16 + lgkmcnt +
// 8x ds_read_b128, ~150-200 cyc RAW round trip) with an all-VALU 64-lane
// all-gather: DPP permutes (xor1/xor2/xor7/xor8) + gfx950 permlane swap
// builtins (xor16/xor32). Masks {1,2,7,8,16,32} span all 6 lane bits ->
// 32 h2 regs holding all 64 tanh values, zero LDS on the critical path.
//
// Hardening vs round 1 (which aborted):
//  - documented builtins __builtin_amdgcn_permlane{16,32}_swap instead of
//    hand-rolled inline asm (with ds_swizzle/ds_bpermute fallbacks);
//  - gather value order discovered at setup (payload = lane index) and folded
//    into permuted f16 weight tables; indices masked &63 -> no OOB possible;
//  - 64-bit coverage check on the discovered permutation; if incomplete, a
//    wave-uniform branch runs the verified round-0 LDS-broadcast path.

constexpr int HID  = 64;
constexpr int INF  = 16;
constexpr int SLEN = 1024;

typedef __fp16 h2_t __attribute__((ext_vector_type(2)));
typedef unsigned u32x2_t __attribute__((ext_vector_type(2)));

template<int CTRL>
__device__ __forceinline__ unsigned dppmov(unsigned v) {
    return (unsigned)__builtin_amdgcn_update_dpp(0, (int)v, CTRL, 0xF, 0xF, true);
}

// {o0,o1} = {self, lane^32 partner} of `in`, per-lane order unspecified
// (discovery at setup absorbs whatever the hardware does).
__device__ __forceinline__ void xor32pair(unsigned in, unsigned& o0, unsigned& o1) {
#if __has_builtin(__builtin_amdgcn_permlane32_swap)
    u32x2_t r = __builtin_amdgcn_permlane32_swap(in, in, false, false);
    o0 = r[0]; o1 = r[1];
#else
    o0 = in;
    o1 = (unsigned)__builtin_amdgcn_ds_bpermute((int)((threadIdx.x ^ 32u) << 2), (int)in);
#endif
}

__device__ __forceinline__ void xor16pair(unsigned in, unsigned& o0, unsigned& o1) {
#if __has_builtin(__builtin_amdgcn_permlane16_swap)
    u32x2_t r = __builtin_amdgcn_permlane16_swap(in, in, false, false);
    o0 = r[0]; o1 = r[1];
#else
    o0 = in;
    o1 = (unsigned)__builtin_amdgcn_ds_swizzle((int)in, 0x401F); // xor lane^16
#endif
}

// All-gather: every lane ends with all 64 lanes' f16(t) in g[0..31] (h2 pairs)
// in a fixed lane-dependent order. ~37 VALU instructions.
__device__ __forceinline__ void gather64(float t, unsigned g[32]) {
    unsigned th = (unsigned)__builtin_bit_cast(unsigned short, (__fp16)t);
    unsigned tp = dppmov<0xB1>(th);            // quad_perm [1,0,3,2] = lane^1
    unsigned p0 = (tp << 16) | th;             // h2 {self, ^1}
    unsigned q0, q1;
    xor32pair(p0, q0, q1);                     // 1 -> 2 regs (adds ^32)
    xor16pair(q0, g[0], g[1]);                 // 2 -> 4 regs (adds ^16)
    xor16pair(q1, g[2], g[3]);
    #pragma unroll
    for (int i = 0; i < 4; ++i)  g[4+i]  = dppmov<0x4E>(g[i]);   // quad [2,3,0,1] = ^2
    #pragma unroll
    for (int i = 0; i < 8; ++i)  g[8+i]  = dppmov<0x141>(g[i]);  // row_half_mirror = ^7
    #pragma unroll
    for (int i = 0; i < 16; ++i) g[16+i] = dppmov<0x128>(g[i]);  // row_ror:8 = ^8
}

__device__ __forceinline__ float fdot(unsigned a, h2_t w, float acc) {
    return __builtin_amdgcn_fdot2(__builtin_bit_cast(h2_t, a), w, acc, false);
}

__device__ __forceinline__ float fast_tanh(float x) {
    // tanh(x) = 1 - 2/(e^{2x}+1); exact limits at +/-inf, no clamp needed.
    float e = __builtin_amdgcn_exp2f(x * 2.8853900817779268f); // 2*log2(e)
    float r = __builtin_amdgcn_rcpf(e + 1.0f);
    return fmaf(-2.0f, r, 1.0f);
}

__global__ __launch_bounds__(64, 1) void lnn_dpp2_kernel(
    const float* __restrict__ x,
    const float* __restrict__ W_in,
    const float* __restrict__ b_in,
    const float* __restrict__ W_hh,
    const float* __restrict__ W_ih,
    const float* __restrict__ bias,
    const float* __restrict__ tau,
    const float* __restrict__ W_out,
    const float* __restrict__ b_out,
    float* __restrict__ out)
{
    const int lane = threadIdx.x;        // hidden index
    const int b    = blockIdx.x;         // batch index

    __shared__ __fp16 th_s[HID];         // used only by the fallback path

    const float rtau = 1.0f / tau[lane];

    // --- input-projection row: Wc = (W_ih @ W_in) row, cbase = folded bias ---
    float Wc[INF];
    #pragma unroll
    for (int k = 0; k < INF; ++k) Wc[k] = 0.0f;
    float bcomb = 0.0f;
    for (int j = 0; j < HID; ++j) {
        float wij = W_ih[lane * HID + j];
        bcomb = fmaf(wij, b_in[j], bcomb);
        #pragma unroll
        for (int k = 0; k < INF; ++k) Wc[k] = fmaf(wij, W_in[j * INF + k], Wc[k]);
    }
    const float cbase = bcomb + bias[lane];
    const float bo    = b_out[0];

    float cr = 0.0f;                     // c_step * rtau (written by run_chain)

    const float hsub  = (1.0f / 1023.0f) * 0.25f;  // dt/N_SUB, dt = 1/1023
    const float hsubh = 0.5f * hsub;
    const float h6    = hsub * (1.0f / 6.0f);

    const float4* xrow = (const float4*)(x + (size_t)b * SLEN * INF);
    float* orow = out + (size_t)b * SLEN;

    // generic time loop; odef(y), odef_out(y, os&), outdot(h) supplied per path
    auto run_chain = [&](auto&& odef, auto&& odef_out, auto&& outdot) {
        float h = 0.0f;
        if (lane == 0) orow[0] = bo;     // dt=0 at s=0 -> h stays 0
        float4 xp0 = xrow[4], xp1 = xrow[5], xp2 = xrow[6], xp3 = xrow[7];

        for (int s = 1; s < SLEN; ++s) {
            {   // c*rtau for this step from prefetched regs
                float cA = fmaf(xp0.x, Wc[0], fmaf(xp0.y, Wc[1],
                           fmaf(xp0.z, Wc[2], fmaf(xp0.w, Wc[3], cbase))));
                float cB = fmaf(xp1.x, Wc[4], fmaf(xp1.y, Wc[5],
                           fmaf(xp1.z, Wc[6], xp1.w * Wc[7])));
                float cC = fmaf(xp2.x, Wc[8], fmaf(xp2.y, Wc[9],
                           fmaf(xp2.z, Wc[10], xp2.w * Wc[11])));
                float cD = fmaf(xp3.x, Wc[12], fmaf(xp3.y, Wc[13],
                           fmaf(xp3.z, Wc[14], xp3.w * Wc[15])));
                cr = ((cA + cB) + (cC + cD)) * rtau;
            }
            {   // prefetch next step's x (hidden behind the 16 evals below)
                int sn = (s < SLEN - 1) ? (s + 1) : (SLEN - 1);
                xp0 = xrow[sn*4+0]; xp1 = xrow[sn*4+1];
                xp2 = xrow[sn*4+2]; xp3 = xrow[sn*4+3];
            }
            {   // substep 0: first eval also yields previous step's output
                float os;
                float k1 = odef_out(h, os);
                if (lane == 0) orow[s - 1] = os + bo;
                float ks = k1;
                float k2 = odef(fmaf(hsubh, k1, h)); ks = fmaf(2.0f, k2, ks);
                float k3 = odef(fmaf(hsubh, k2, h)); ks = fmaf(2.0f, k3, ks);
                float k4 = odef(fmaf(hsub,  k3, h)); ks += k4;
                h = fmaf(h6, ks, h);
            }
            #pragma unroll
            for (int sub = 1; sub < 4; ++sub) {
                float k1 = odef(h);
                float ks = k1;
                float k2 = odef(fmaf(hsubh, k1, h)); ks = fmaf(2.0f, k2, ks);
                float k3 = odef(fmaf(hsubh, k2, h)); ks = fmaf(2.0f, k3, ks);
                float k4 = odef(fmaf(hsub,  k3, h)); ks += k4;
                h = fmaf(h6, ks, h);
            }
        }
        float ofin = outdot(h);          // all lanes (cross-lane inside)
        if (lane == 0) orow[SLEN - 1] = ofin + bo;
    };

    // --- discover the gather network's per-lane value order -----------------
    unsigned gd[32];
    gather64((float)lane, gd);           // payload = lane index, exact in f16
    unsigned long long cov = 0ull;
    #pragma unroll
    for (int r = 0; r < 32; ++r) {
        h2_t pr = __builtin_bit_cast(h2_t, gd[r]);
        int j0 = ((int)(float)pr[0]) & 63;   // masked: OOB impossible
        int j1 = ((int)(float)pr[1]) & 63;
        cov |= (1ull << j0);
        cov |= (1ull << j1);
    }
    const bool fastok = (__all(cov == 0xFFFFFFFFFFFFFFFFull) != 0);

    if (fastok) {
        // permuted f16 weight tables matching the gather's value order
        h2_t whp[HID / 2], wovp[HID / 2];
        const float* wrow = W_hh + lane * HID;
        #pragma unroll
        for (int r = 0; r < 32; ++r) {
            h2_t pr = __builtin_bit_cast(h2_t, gd[r]);
            int j0 = ((int)(float)pr[0]) & 63;
            int j1 = ((int)(float)pr[1]) & 63;
            whp[r]  = __builtin_amdgcn_cvt_pkrtz(wrow[j0] * rtau, wrow[j1] * rtau);
            wovp[r] = __builtin_amdgcn_cvt_pkrtz(W_out[j0], W_out[j1]);
        }

        auto odef = [&](float y) -> float {
            float cmy = fmaf(-rtau, y, cr);   // parallel to tanh chain
            float t = fast_tanh(y);
            unsigned g[32];
            gather64(t, g);
            float a0 = cmy, a1 = 0.f, a2 = 0.f, a3 = 0.f;
            #pragma unroll
            for (int q = 0; q < 8; ++q) {
                a0 = fdot(g[4*q+0], whp[4*q+0], a0);
                a1 = fdot(g[4*q+1], whp[4*q+1], a1);
                a2 = fdot(g[4*q+2], whp[4*q+2], a2);
                a3 = fdot(g[4*q+3], whp[4*q+3], a3);
            }
            return (a0 + a1) + (a2 + a3);
        };
        auto odef_out = [&](float y, float& os) -> float {
            float cmy = fmaf(-rtau, y, cr);
            float t = fast_tanh(y);
            unsigned g[32];
            gather64(t, g);
            float a0 = cmy, a1 = 0.f, a2 = 0.f, a3 = 0.f;
            float o0 = 0.f, o1 = 0.f, o2 = 0.f, o3 = 0.f;
            #pragma unroll
            for (int q = 0; q < 8; ++q) {     // same gathered regs feed both dots
                a0 = fdot(g[4*q+0], whp[4*q+0], a0);
                a1 = fdot(g[4*q+1], whp[4*q+1], a1);
                a2 = fdot(g[4*q+2], whp[4*q+2], a2);
                a3 = fdot(g[4*q+3], whp[4*q+3], a3);
                o0 = fdot(g[4*q+0], wovp[4*q+0], o0);
                o1 = fdot(g[4*q+1], wovp[4*q+1], o1);
                o2 = fdot(g[4*q+2], wovp[4*q+2], o2);
                o3 = fdot(g[4*q+3], wovp[4*q+3], o3);
            }
            os = (o0 + o1) + (o2 + o3);
            return (a0 + a1) + (a2 + a3);
        };
        auto outdot = [&](float hf) -> float {
            float t = fast_tanh(hf);
            unsigned g[32];
            gather64(t, g);
            float o0 = 0.f, o1 = 0.f, o2 = 0.f, o3 = 0.f;
            #pragma unroll
            for (int q = 0; q < 8; ++q) {
                o0 = fdot(g[4*q+0], wovp[4*q+0], o0);
                o1 = fdot(g[4*q+1], wovp[4*q+1], o1);
                o2 = fdot(g[4*q+2], wovp[4*q+2], o2);
                o3 = fdot(g[4*q+3], wovp[4*q+3], o3);
            }
            return (o0 + o1) + (o2 + o3);
        };
        run_chain(odef, odef_out, outdot);
    } else {
        // fallback: verified round-0 LDS-broadcast path (in-order tables)
        h2_t wh[HID / 2], wov[HID / 2];
        {
            const float4* w4 = (const float4*)(W_hh + lane * HID);
            const float4* o4 = (const float4*)(W_out);
            #pragma unroll
            for (int q = 0; q < HID / 4; ++q) {
                float4 v = w4[q];
                wh[2*q+0] = __builtin_amdgcn_cvt_pkrtz(v.x * rtau, v.y * rtau);
                wh[2*q+1] = __builtin_amdgcn_cvt_pkrtz(v.z * rtau, v.w * rtau);
                float4 o = o4[q];
                wov[2*q+0] = __builtin_amdgcn_cvt_pkrtz(o.x, o.y);
                wov[2*q+1] = __builtin_amdgcn_cvt_pkrtz(o.z, o.w);
            }
        }
        auto odef = [&](float y) -> float {
            float cmy = fmaf(-rtau, y, cr);
            float t = fast_tanh(y);
            th_s[lane] = (__fp16)t;
            float a0 = cmy, a1 = 0.f, a2 = 0.f, a3 = 0.f;
            const uint4* t4 = (const uint4*)th_s;
            #pragma unroll
            for (int q = 0; q < 8; ++q) {
                uint4 r = t4[q];
                a0 = fdot(r.x, wh[4*q+0], a0);
                a1 = fdot(r.y, wh[4*q+1], a1);
                a2 = fdot(r.z, wh[4*q+2], a2);
                a3 = fdot(r.w, wh[4*q+3], a3);
            }
            return (a0 + a1) + (a2 + a3);
        };
        auto odef_out = [&](float y, float& os) -> float {
            float cmy = fmaf(-rtau, y, cr);
            float t = fast_tanh(y);
            th_s[lane] = (__fp16)t;
            float a0 = cmy, a1 = 0.f, a2 = 0.f, a3 = 0.f;
            float o0 = 0.f, o1 = 0.f, o2 = 0.f, o3 = 0.f;
            const uint4* t4 = (const uint4*)th_s;
            #pragma unroll
            for (int q = 0; q < 8; ++q) {
                uint4 r = t4[q];
                a0 = fdot(r.x, wh[4*q+0], a0);
                a1 = fdot(r.y, wh[4*q+1], a1);
                a2 = fdot(r.z, wh[4*q+2], a2);
                a3 = fdot(r.w, wh[4*q+3], a3);
                o0 = fdot(r.x, wov[4*q+0], o0);
                o1 = fdot(r.y, wov[4*q+1], o1);
                o2 = fdot(r.z, wov[4*q+2], o2);
                o3 = fdot(r.w, wov[4*q+3], o3);
            }
            os = (o0 + o1) + (o2 + o3);
            return (a0 + a1) + (a2 + a3);
        };
        auto outdot = [&](float hf) -> float {
            float t = fast_tanh(hf);
            th_s[lane] = (__fp16)t;
            float o0 = 0.f, o1 = 0.f, o2 = 0.f, o3 = 0.f;
            const uint4* t4 = (const uint4*)th_s;
            #pragma unroll
            for (int q = 0; q < 8; ++q) {
                uint4 r = t4[q];
                o0 = fdot(r.x, wov[4*q+0], o0);
                o1 = fdot(r.y, wov[4*q+1], o1);
                o2 = fdot(r.z, wov[4*q+2], o2);
                o3 = fdot(r.w, wov[4*q+3], o3);
            }
            return (o0 + o1) + (o2 + o3);
        };
        run_chain(odef, odef_out, outdot);
    }
}

extern "C" void kernel_launch(void* const* d_in, const int* in_sizes, int n_in,
                              void* d_out, int out_size, void* d_ws, size_t ws_size,
                              hipStream_t stream) {
    const float* x     = (const float*)d_in[0];
    const float* W_in  = (const float*)d_in[1];
    const float* b_in  = (const float*)d_in[2];
    const float* W_hh  = (const float*)d_in[3];
    const float* W_ih  = (const float*)d_in[4];
    const float* bias  = (const float*)d_in[5];
    const float* tau   = (const float*)d_in[6];
    const float* W_out = (const float*)d_in[7];
    const float* b_out = (const float*)d_in[8];
    float* out = (float*)d_out;

    lnn_dpp2_kernel<<<512, 64, 0, stream>>>(x, W_in, b_in, W_hh, W_ih, bias,
                                            tau, W_out, b_out, out);
}

// Round 3
// 2851.460 us; speedup vs baseline: 1.0948x; 1.0948x over previous
//
#include <hip/hip_runtime.h>

// LiquidNeuralNetwork: B=512, S=1024, IN=16, HID=64, OUT=1, N_SUB=4 (RK4).
// One chain per wave (512 blocks x 64 thr), latency/issue-bound serial chain.
//
// Round-3 theory: round 2 (DPP all-gather) == round 0 (LDS broadcast) at
// ~333 cyc/eval, consistent with single-wave issue cadence ~4 cyc/instr:
// wall ~= 4*N_instr + exposed stalls. So minimize instructions on the chain.
//
// 4-way split dot: lane l computes 4 partial dots (outputs l^0,l^16,l^32,l^48)
// over ONLY its 16-lane group's elements:
//   - in-group gather: DPP masks {1,2,7,8} span lane bits 0-3 -> 10 ops
//     (vs 37 for the full 64-gather), 8 h2 regs;
//   - 32 fdot2 (4 slots x 8), chains depth 4;
//   - 2-level butterfly combine (permlane32_swap x2 + permlane16_swap x1 +
//     adds) returns each output's full dot to its home lane.
// ~63 VALU/eval vs ~85 -> predicted ~2.4-2.7 ms.
//
// Safety: gather value order, swap partner-slot mode, and the full combine
// network are verified at setup (exact integer payloads); any mismatch falls
// back wave-uniformly to the verified round-0 LDS-broadcast path.

constexpr int HID  = 64;
constexpr int INF  = 16;
constexpr int SLEN = 1024;

typedef __fp16 h2_t __attribute__((ext_vector_type(2)));
typedef unsigned u32x2_t __attribute__((ext_vector_type(2)));

template<int CTRL>
__device__ __forceinline__ unsigned dppmov(unsigned v) {
    return (unsigned)__builtin_amdgcn_update_dpp(0, (int)v, CTRL, 0xF, 0xF, true);
}

__device__ __forceinline__ float fdot(unsigned a, h2_t w, float acc) {
    return __builtin_amdgcn_fdot2(__builtin_bit_cast(h2_t, a), w, acc, false);
}

__device__ __forceinline__ float fast_tanh(float x) {
    // tanh(x) = 1 - 2/(e^{2x}+1); exact limits at +/-inf, no clamp needed.
    float e = __builtin_amdgcn_exp2f(x * 2.8853900817779268f); // 2*log2(e)
    float r = __builtin_amdgcn_rcpf(e + 1.0f);
    return fmaf(-2.0f, r, 1.0f);
}

// In-group all-gather: after this, lane l holds all 16 values of its 16-lane
// group (lanes l&~15 .. |15) as 8 h2 regs, lane-dependent order (discovered).
__device__ __forceinline__ void gatherG(float t, unsigned g[8]) {
    unsigned th = (unsigned)__builtin_bit_cast(unsigned short, (__fp16)t);
    unsigned tp = dppmov<0xB1>(th);            // quad_perm [1,0,3,2] = ^1
    g[0] = (tp << 16) | th;                    // h2 {self, ^1}
    g[1] = dppmov<0x4E>(g[0]);                 // quad_perm [2,3,0,1] = ^2
    g[2] = dppmov<0x141>(g[0]);                // row_half_mirror = ^7
    g[3] = dppmov<0x141>(g[1]);
    g[4] = dppmov<0x128>(g[0]);                // row_ror:8 = ^8
    g[5] = dppmov<0x128>(g[1]);
    g[6] = dppmov<0x128>(g[2]);
    g[7] = dppmov<0x128>(g[3]);
}

__global__ __launch_bounds__(64, 1) void lnn_split4_kernel(
    const float* __restrict__ x,
    const float* __restrict__ W_in,
    const float* __restrict__ b_in,
    const float* __restrict__ W_hh,
    const float* __restrict__ W_ih,
    const float* __restrict__ bias,
    const float* __restrict__ tau,
    const float* __restrict__ W_out,
    const float* __restrict__ b_out,
    float* __restrict__ out)
{
    const int lane = threadIdx.x;        // hidden index (home of state h_lane)
    const int b    = blockIdx.x;         // batch index

    __shared__ __fp16 th_s[HID];         // used only by the fallback path

    const float rtau = 1.0f / tau[lane];

    // --- input-projection row: Wc = (W_ih @ W_in) row, cbase = folded bias ---
    float Wc[INF];
    #pragma unroll
    for (int k = 0; k < INF; ++k) Wc[k] = 0.0f;
    float bcomb = 0.0f;
    for (int j = 0; j < HID; ++j) {
        float wij = W_ih[lane * HID + j];
        bcomb = fmaf(wij, b_in[j], bcomb);
        #pragma unroll
        for (int k = 0; k < INF; ++k) Wc[k] = fmaf(wij, W_in[j * INF + k], Wc[k]);
    }
    const float cbase = bcomb + bias[lane];
    const float bo    = b_out[0];

    float cr = 0.0f;                     // c_step * rtau (written by run_chain)

    const float hsub  = (1.0f / 1023.0f) * 0.25f;  // dt/N_SUB, dt = 1/1023
    const float hsubh = 0.5f * hsub;
    const float h6    = hsub * (1.0f / 6.0f);

    const float4* xrow = (const float4*)(x + (size_t)b * SLEN * INF);
    float* orow = out + (size_t)b * SLEN;

    // generic time loop; odef(y), odef_out(y, os&), outdot(h) supplied per path
    auto run_chain = [&](auto&& odef, auto&& odef_out, auto&& outdot) {
        float h = 0.0f;
        if (lane == 0) orow[0] = bo;     // dt=0 at s=0 -> h stays 0
        float4 xp0 = xrow[4], xp1 = xrow[5], xp2 = xrow[6], xp3 = xrow[7];

        for (int s = 1; s < SLEN; ++s) {
            {   // c*rtau for this step from prefetched regs
                float cA = fmaf(xp0.x, Wc[0], fmaf(xp0.y, Wc[1],
                           fmaf(xp0.z, Wc[2], fmaf(xp0.w, Wc[3], cbase))));
                float cB = fmaf(xp1.x, Wc[4], fmaf(xp1.y, Wc[5],
                           fmaf(xp1.z, Wc[6], xp1.w * Wc[7])));
                float cC = fmaf(xp2.x, Wc[8], fmaf(xp2.y, Wc[9],
                           fmaf(xp2.z, Wc[10], xp2.w * Wc[11])));
                float cD = fmaf(xp3.x, Wc[12], fmaf(xp3.y, Wc[13],
                           fmaf(xp3.z, Wc[14], xp3.w * Wc[15])));
                cr = ((cA + cB) + (cC + cD)) * rtau;
            }
            {   // prefetch next step's x (hidden behind the 16 evals below)
                int sn = (s < SLEN - 1) ? (s + 1) : (SLEN - 1);
                xp0 = xrow[sn*4+0]; xp1 = xrow[sn*4+1];
                xp2 = xrow[sn*4+2]; xp3 = xrow[sn*4+3];
            }
            {   // substep 0: first eval also yields previous step's output
                float os;
                float k1 = odef_out(h, os);
                if (lane == 0) orow[s - 1] = os + bo;
                float ks = k1;
                float k2 = odef(fmaf(hsubh, k1, h)); ks = fmaf(2.0f, k2, ks);
                float k3 = odef(fmaf(hsubh, k2, h)); ks = fmaf(2.0f, k3, ks);
                float k4 = odef(fmaf(hsub,  k3, h)); ks += k4;
                h = fmaf(h6, ks, h);
            }
            #pragma unroll
            for (int sub = 1; sub < 4; ++sub) {
                float k1 = odef(h);
                float ks = k1;
                float k2 = odef(fmaf(hsubh, k1, h)); ks = fmaf(2.0f, k2, ks);
                float k3 = odef(fmaf(hsubh, k2, h)); ks = fmaf(2.0f, k3, ks);
                float k4 = odef(fmaf(hsub,  k3, h)); ks += k4;
                h = fmaf(h6, ks, h);
            }
        }
        float ofin = outdot(h);          // all lanes (cross-lane inside)
        if (lane == 0) orow[SLEN - 1] = ofin + bo;
    };

    // --- discovery: in-group gather order + swap partner-slot modes ---------
    unsigned gd[8];
    gatherG((float)lane, gd);            // payload = lane index, exact in f16
    int e0[8], e1[8];
    unsigned covm = 0;
    #pragma unroll
    for (int r = 0; r < 8; ++r) {
        h2_t pr = __builtin_bit_cast(h2_t, gd[r]);
        e0[r] = (((int)(float)pr[0]) & 15) | (lane & 48);  // forced in-group
        e1[r] = (((int)(float)pr[1]) & 15) | (lane & 48);
        covm |= 1u << (e0[r] & 15);
        covm |= 1u << (e1[r] & 15);
    }
    const bool gok = (__all(covm == 0xFFFFu) != 0);

    // permlane swap partner-slot discovery (which output reg holds partner)
    const bool hi32 = (lane & 32) != 0;
    const bool hi16 = (lane & 16) != 0;
    u32x2_t r32 = __builtin_amdgcn_permlane32_swap((unsigned)lane, (unsigned)lane, false, false);
    const bool m32A = (__all((int)(hi32 ? r32[0] : r32[1]) == (lane ^ 32)) != 0);
    const bool m32B = (__all((int)(hi32 ? r32[1] : r32[0]) == (lane ^ 32)) != 0);
    const bool ok32 = m32A || m32B;
    const bool p32_r0 = m32A ? hi32 : !hi32;   // per-lane: partner in r[0]?

    u32x2_t r16 = __builtin_amdgcn_permlane16_swap((unsigned)lane, (unsigned)lane, false, false);
    const bool m16A = (__all((int)(hi16 ? r16[0] : r16[1]) == (lane ^ 16)) != 0);
    const bool m16B = (__all((int)(hi16 ? r16[1] : r16[0]) == (lane ^ 16)) != 0);
    const bool ok16 = m16A || m16B;
    const bool p16_r0 = m16A ? hi16 : !hi16;

    auto partner32 = [&](float v) -> float {
        unsigned u = __builtin_bit_cast(unsigned, v);
        u32x2_t r = __builtin_amdgcn_permlane32_swap(u, u, false, false);
        return __builtin_bit_cast(float, p32_r0 ? r[0] : r[1]);
    };
    auto partner16 = [&](float v) -> float {
        unsigned u = __builtin_bit_cast(unsigned, v);
        u32x2_t r = __builtin_amdgcn_permlane16_swap(u, u, false, false);
        return __builtin_bit_cast(float, p16_r0 ? r[0] : r[1]);
    };
    // butterfly combine: P[k] = partial for output lane^(k<<4) over my group's
    // 16 elements; returns full dot for output `lane`.
    auto comb4 = [&](float P0, float P1, float P2, float P3) -> float {
        float Q0 = P0 + partner32(P2);
        float Q1 = P1 + partner32(P3);
        return Q0 + partner16(Q1);
    };
    auto allsum4 = [&](float v) -> float {   // sum over the 4 group-partners
        float a = v + partner32(v);
        return a + partner16(a);
    };

    // end-to-end combine self-test with exact integer payloads
    bool cok;
    {
        float P0 = (float)lane;
        float P1 = (float)(lane ^ 16) + 0.0f + 64.0f * 1.0f - (float)(lane ^ 16) + (float)lane + 64.0f; // = lane + 64
        // (simplify: P_k at lane l must equal l + 64k for the algebra below)
        P1 = (float)lane + 64.0f;
        float P2 = (float)lane + 128.0f;
        float P3 = (float)lane + 192.0f;
        float got = comb4(P0, P1, P2, P3);
        // expected: l + [(l^32)+128] + [(l^16)+64] + [(l^48)+192]
        float T = (float)lane + (float)(lane ^ 16) + (float)(lane ^ 32)
                + (float)(lane ^ 48) + 384.0f;
        cok = (__all(got == T) != 0);
    }

    const bool fastok = gok && ok32 && ok16 && cok;

    if (fastok) {
        // --- per-lane weight tables -----------------------------------------
        // whp[k][r]: h2 of W_hh[o_k][e(r,*)] * rtau[o_k], o_k = lane^(k<<4),
        // elements in the discovered gather order of MY group.
        h2_t whp[4][8];
        #pragma unroll
        for (int k = 0; k < 4; ++k) {
            int o = lane ^ (k << 4);
            float rt = 1.0f / tau[o];
            const float* wrow = W_hh + o * HID;
            #pragma unroll
            for (int r = 0; r < 8; ++r) {
                whp[k][r] = __builtin_amdgcn_cvt_pkrtz(wrow[e0[r]] * rt,
                                                       wrow[e1[r]] * rt);
            }
        }
        h2_t wovp[8];                    // W_out over my group's elements
        #pragma unroll
        for (int r = 0; r < 8; ++r)
            wovp[r] = __builtin_amdgcn_cvt_pkrtz(W_out[e0[r]], W_out[e1[r]]);

        auto odef = [&](float y) -> float {
            float cmy = fmaf(-rtau, y, cr);   // own output's (c-y)*rtau term
            float t = fast_tanh(y);
            unsigned g[8];
            gatherG(t, g);
            float P[4];
            #pragma unroll
            for (int k = 0; k < 4; ++k) {
                float u = (k == 0) ? cmy : 0.0f;
                float v = 0.0f;
                u = fdot(g[0], whp[k][0], u); v = fdot(g[1], whp[k][1], v);
                u = fdot(g[2], whp[k][2], u); v = fdot(g[3], whp[k][3], v);
                u = fdot(g[4], whp[k][4], u); v = fdot(g[5], whp[k][5], v);
                u = fdot(g[6], whp[k][6], u); v = fdot(g[7], whp[k][7], v);
                P[k] = u + v;
            }
            return comb4(P[0], P[1], P[2], P[3]);
        };
        auto odef_out = [&](float y, float& os) -> float {
            float cmy = fmaf(-rtau, y, cr);
            float t = fast_tanh(y);
            unsigned g[8];
            gatherG(t, g);
            float P[4];
            #pragma unroll
            for (int k = 0; k < 4; ++k) {
                float u = (k == 0) ? cmy : 0.0f;
                float v = 0.0f;
                u = fdot(g[0], whp[k][0], u); v = fdot(g[1], whp[k][1], v);
                u = fdot(g[2], whp[k][2], u); v = fdot(g[3], whp[k][3], v);
                u = fdot(g[4], whp[k][4], u); v = fdot(g[5], whp[k][5], v);
                u = fdot(g[6], whp[k][6], u); v = fdot(g[7], whp[k][7], v);
                P[k] = u + v;
            }
            float o0 = 0.f, o1 = 0.f;         // output-dot partial (my group)
            o0 = fdot(g[0], wovp[0], o0); o1 = fdot(g[1], wovp[1], o1);
            o0 = fdot(g[2], wovp[2], o0); o1 = fdot(g[3], wovp[3], o1);
            o0 = fdot(g[4], wovp[4], o0); o1 = fdot(g[5], wovp[5], o1);
            o0 = fdot(g[6], wovp[6], o0); o1 = fdot(g[7], wovp[7], o1);
            os = allsum4(o0 + o1);
            return comb4(P[0], P[1], P[2], P[3]);
        };
        auto outdot = [&](float hf) -> float {
            float t = fast_tanh(hf);
            unsigned g[8];
            gatherG(t, g);
            float o0 = 0.f, o1 = 0.f;
            o0 = fdot(g[0], wovp[0], o0); o1 = fdot(g[1], wovp[1], o1);
            o0 = fdot(g[2], wovp[2], o0); o1 = fdot(g[3], wovp[3], o1);
            o0 = fdot(g[4], wovp[4], o0); o1 = fdot(g[5], wovp[5], o1);
            o0 = fdot(g[6], wovp[6], o0); o1 = fdot(g[7], wovp[7], o1);
            return allsum4(o0 + o1);
        };
        run_chain(odef, odef_out, outdot);
    } else {
        // fallback: verified round-0 LDS-broadcast path (in-order tables)
        h2_t wh[HID / 2], wov[HID / 2];
        {
            const float4* w4 = (const float4*)(W_hh + lane * HID);
            const float4* o4 = (const float4*)(W_out);
            #pragma unroll
            for (int q = 0; q < HID / 4; ++q) {
                float4 v = w4[q];
                wh[2*q+0] = __builtin_amdgcn_cvt_pkrtz(v.x * rtau, v.y * rtau);
                wh[2*q+1] = __builtin_amdgcn_cvt_pkrtz(v.z * rtau, v.w * rtau);
                float4 o = o4[q];
                wov[2*q+0] = __builtin_amdgcn_cvt_pkrtz(o.x, o.y);
                wov[2*q+1] = __builtin_amdgcn_cvt_pkrtz(o.z, o.w);
            }
        }
        auto odef = [&](float y) -> float {
            float cmy = fmaf(-rtau, y, cr);
            float t = fast_tanh(y);
            th_s[lane] = (__fp16)t;
            float a0 = cmy, a1 = 0.f, a2 = 0.f, a3 = 0.f;
            const uint4* t4 = (const uint4*)th_s;
            #pragma unroll
            for (int q = 0; q < 8; ++q) {
                uint4 r = t4[q];
                a0 = fdot(r.x, wh[4*q+0], a0);
                a1 = fdot(r.y, wh[4*q+1], a1);
                a2 = fdot(r.z, wh[4*q+2], a2);
                a3 = fdot(r.w, wh[4*q+3], a3);
            }
            return (a0 + a1) + (a2 + a3);
        };
        auto odef_out = [&](float y, float& os) -> float {
            float cmy = fmaf(-rtau, y, cr);
            float t = fast_tanh(y);
            th_s[lane] = (__fp16)t;
            float a0 = cmy, a1 = 0.f, a2 = 0.f, a3 = 0.f;
            float o0 = 0.f, o1 = 0.f, o2 = 0.f, o3 = 0.f;
            const uint4* t4 = (const uint4*)th_s;
            #pragma unroll
            for (int q = 0; q < 8; ++q) {
                uint4 r = t4[q];
                a0 = fdot(r.x, wh[4*q+0], a0);
                a1 = fdot(r.y, wh[4*q+1], a1);
                a2 = fdot(r.z, wh[4*q+2], a2);
                a3 = fdot(r.w, wh[4*q+3], a3);
                o0 = fdot(r.x, wov[4*q+0], o0);
                o1 = fdot(r.y, wov[4*q+1], o1);
                o2 = fdot(r.z, wov[4*q+2], o2);
                o3 = fdot(r.w, wov[4*q+3], o3);
            }
            os = (o0 + o1) + (o2 + o3);
            return (a0 + a1) + (a2 + a3);
        };
        auto outdot = [&](float hf) -> float {
            float t = fast_tanh(hf);
            th_s[lane] = (__fp16)t;
            float o0 = 0.f, o1 = 0.f, o2 = 0.f, o3 = 0.f;
            const uint4* t4 = (const uint4*)th_s;
            #pragma unroll
            for (int q = 0; q < 8; ++q) {
                uint4 r = t4[q];
                o0 = fdot(r.x, wov[4*q+0], o0);
                o1 = fdot(r.y, wov[4*q+1], o1);
                o2 = fdot(r.z, wov[4*q+2], o2);
                o3 = fdot(r.w, wov[4*q+3], o3);
            }
            return (o0 + o1) + (o2 + o3);
        };
        run_chain(odef, odef_out, outdot);
    }
}

extern "C" void kernel_launch(void* const* d_in, const int* in_sizes, int n_in,
                              void* d_out, int out_size, void* d_ws, size_t ws_size,
                              hipStream_t stream) {
    const float* x     = (const float*)d_in[0];
    const float* W_in  = (const float*)d_in[1];
    const float* b_in  = (const float*)d_in[2];
    const float* W_hh  = (const float*)d_in[3];
    const float* W_ih  = (const float*)d_in[4];
    const float* bias  = (const float*)d_in[5];
    const float* tau   = (const float*)d_in[6];
    const float* W_out = (const float*)d_in[7];
    const float* b_out = (const float*)d_in[8];
    float* out = (float*)d_out;

    lnn_split4_kernel<<<512, 64, 0, stream>>>(x, W_in, b_in, W_hh, W_ih, bias,
                                              tau, W_out, b_out, out);
}